// Round 1
// baseline (31.371 us; speedup 1.0000x reference)
//
#include <hip/hip_runtime.h>
#include <hip/hip_bf16.h>

// LocalitySelfAttention collapses: diag(+1e9) => softmax is exactly identity
// => out = x @ (w_proj @ W_v)^T + b_proj, W_v = w_qkv[2C:3C,:].
// Kernel A: W_eff = w_proj @ W_v (fp32), stored bf16 in MFMA-B packed layout.
// Kernel B: [8192,256] x [256,256]^T GEMM via mfma_f32_16x16x32_bf16 + bias.

#define C_DIM 256
#define M_ROWS 8192   // B*N = 2*4096

typedef __attribute__((ext_vector_type(8))) short short8;
typedef __attribute__((ext_vector_type(4))) float f32x4;

static __device__ __forceinline__ short f2bf(float f) {
    __hip_bfloat16 h = __float2bfloat16(f);   // RN
    return __builtin_bit_cast(short, h);
}

// ---- Kernel A: W_eff[n][k] = sum_c w_proj[n][c] * w_qkv[2C+c][k], packed ----
// Packed layout (matches B-fragment consumption in kernel B):
//   wpack[((nb*8 + kb)*64 + lane)*8 + i] = W_eff[nb*16+(lane&15)][kb*32+(lane>>4)*8+i]
__global__ void weff_pack_kernel(const float* __restrict__ w_qkv,
                                 const float* __restrict__ w_proj,
                                 short* __restrict__ wpack) {
    const int k = threadIdx.x;      // 0..255 (k index)
    const int n = blockIdx.x;       // 0..255 (output row of W_eff)
    const float* __restrict__ wv = w_qkv + 2 * C_DIM * C_DIM;  // V-projection rows
    const float* __restrict__ wp = w_proj + n * C_DIM;
    float acc = 0.f;
#pragma unroll 8
    for (int c = 0; c < C_DIM; ++c) {
        acc += wp[c] * wv[c * C_DIM + k];   // wp[c] wave-uniform (s_load), wv coalesced
    }
    const int nb = n >> 4, ln = n & 15;
    const int kb = k >> 5, hi = (k >> 3) & 3, i = k & 7;
    const int lane = hi * 16 + ln;
    wpack[(size_t)(((nb * 8 + kb) * 64) + lane) * 8 + i] = f2bf(acc);
}

// ---- Kernel B: out[m][n] = sum_k x[m][k]*W_eff[n][k] + b_proj[n] ----
// 2 waves/block, 16 rows per wave, full N=256 per wave (16 n-blocks).
__global__ void __launch_bounds__(128) out_gemm_kernel(
        const float* __restrict__ x,
        const short* __restrict__ wpack,
        const float* __restrict__ b_proj,
        float* __restrict__ out) {
    const int lane = threadIdx.x & 63;
    const int wid  = threadIdx.x >> 6;          // 0..1
    const int lr = lane & 15;                   // row (A) / col (B,C)
    const int hi = lane >> 4;                   // k-group
    const int m0 = blockIdx.x * 32 + wid * 16;  // this wave's 16-row strip

    // A fragments: a[kb][j] = bf16(x[m0+lr][kb*32 + hi*8 + j])
    short8 a[8];
    const float* __restrict__ xr = x + (size_t)(m0 + lr) * C_DIM;
#pragma unroll
    for (int kb = 0; kb < 8; ++kb) {
        const f32x4* p = reinterpret_cast<const f32x4*>(xr + kb * 32 + hi * 8);
        f32x4 u = p[0];
        f32x4 v = p[1];
        short8 t;
#pragma unroll
        for (int j = 0; j < 4; ++j) {
            t[j]     = f2bf(u[j]);
            t[4 + j] = f2bf(v[j]);
        }
        a[kb] = t;
    }

    const short8* __restrict__ wp8 = reinterpret_cast<const short8*>(wpack);
#pragma unroll 2
    for (int nb = 0; nb < 16; ++nb) {
        f32x4 acc = {0.f, 0.f, 0.f, 0.f};
#pragma unroll
        for (int kb = 0; kb < 8; ++kb) {
            short8 b = wp8[(nb * 8 + kb) * 64 + lane];
            acc = __builtin_amdgcn_mfma_f32_16x16x32_bf16(a[kb], b, acc, 0, 0, 0);
        }
        const float bias = b_proj[nb * 16 + lr];
        // C/D layout (measured): col = lane&15, row = (lane>>4)*4 + reg
#pragma unroll
        for (int r = 0; r < 4; ++r) {
            out[(size_t)(m0 + hi * 4 + r) * C_DIM + nb * 16 + lr] = acc[r] + bias;
        }
    }
}

extern "C" void kernel_launch(void* const* d_in, const int* in_sizes, int n_in,
                              void* d_out, int out_size, void* d_ws, size_t ws_size,
                              hipStream_t stream) {
    const float* x      = (const float*)d_in[0];   // [2,4096,256]
    const float* w_qkv  = (const float*)d_in[1];   // [768,256]
    const float* w_proj = (const float*)d_in[2];   // [256,256]
    const float* b_proj = (const float*)d_in[3];   // [256]
    // d_in[4] = temperature: softmax is exactly one-hot for any T>0 -> unused.
    short* wpack = (short*)d_ws;                   // 256*256 bf16 = 128 KB
    float* out = (float*)d_out;

    hipLaunchKernelGGL(weff_pack_kernel, dim3(256), dim3(256), 0, stream,
                       w_qkv, w_proj, wpack);
    hipLaunchKernelGGL(out_gemm_kernel, dim3(M_ROWS / 32), dim3(128), 0, stream,
                       x, wpack, b_proj, out);
}

// Round 2
// 18.527 us; speedup vs baseline: 1.6932x; 1.6932x over previous
//
#include <hip/hip_runtime.h>
#include <hip/hip_bf16.h>

// LocalitySelfAttention collapses: diag(+1e9) => softmax is exactly identity
// => out = x @ (w_proj @ W_v)^T + b_proj, W_v = w_qkv[2C:3C,:].
// Kernel A: W_eff = w_proj @ W_v (fp32), stored bf16 in MFMA-B packed layout.
// Kernel B: [8192,256] x [256,256]^T GEMM via mfma_f32_16x16x32_bf16 + bias.

#define C_DIM 256
#define M_ROWS 8192   // B*N = 2*4096

typedef __attribute__((ext_vector_type(8))) short short8;
typedef __attribute__((ext_vector_type(4))) float f32x4;

static __device__ __forceinline__ short f2bf(float f) {
    __hip_bfloat16 h = __float2bfloat16(f);   // RN
    return __builtin_bit_cast(short, h);
}

// ---- Kernel A: W_eff[n][k] = sum_c w_proj[n][c] * w_qkv[2C+c][k], packed ----
// Packed layout (matches B-fragment consumption in kernel B):
//   wpack[((nb*8 + kb)*64 + lane)*8 + i] = W_eff[nb*16+(lane&15)][kb*32+(lane>>4)*8+i]
// v2: 4 independent accumulators (dep chain 256 -> 64) and 32 loads in flight.
__global__ void weff_pack_kernel(const float* __restrict__ w_qkv,
                                 const float* __restrict__ w_proj,
                                 short* __restrict__ wpack) {
    const int k = threadIdx.x;      // 0..255 (k index)
    const int n = blockIdx.x;       // 0..255 (output row of W_eff)
    const float* __restrict__ wv = w_qkv + 2 * C_DIM * C_DIM;  // V-projection rows
    const float* __restrict__ wp = w_proj + n * C_DIM;
    float a0 = 0.f, a1 = 0.f, a2 = 0.f, a3 = 0.f;
#pragma unroll 8
    for (int c = 0; c < C_DIM; c += 4) {
        a0 += wp[c + 0] * wv[(size_t)(c + 0) * C_DIM + k];  // wp uniform (s_load)
        a1 += wp[c + 1] * wv[(size_t)(c + 1) * C_DIM + k];  // wv coalesced
        a2 += wp[c + 2] * wv[(size_t)(c + 2) * C_DIM + k];
        a3 += wp[c + 3] * wv[(size_t)(c + 3) * C_DIM + k];
    }
    const float acc = (a0 + a1) + (a2 + a3);
    const int nb = n >> 4, ln = n & 15;
    const int kb = k >> 5, hi = (k >> 3) & 3, i = k & 7;
    const int lane = hi * 16 + ln;
    wpack[(size_t)(((nb * 8 + kb) * 64) + lane) * 8 + i] = f2bf(acc);
}

// ---- Kernel B: out[m][n] = sum_k x[m][k]*W_eff[n][k] + b_proj[n] ----
// v3: 4 waves/block; wave = 16 rows x 128 cols (8 n-blocks). 1024 waves total
// (4 waves/CU, 2x prior occupancy). Waves wid=(s,colhalf) pair on the same
// 16-row strip share x reads via L1. 32 B-loads in flight (unroll 4).
__global__ void __launch_bounds__(256) out_gemm_kernel(
        const float* __restrict__ x,
        const short* __restrict__ wpack,
        const float* __restrict__ b_proj,
        float* __restrict__ out) {
    const int lane = threadIdx.x & 63;
    const int wid  = threadIdx.x >> 6;          // 0..3
    const int lr = lane & 15;                   // row (A) / col (B,C)
    const int hi = lane >> 4;                   // k-group
    const int strip = blockIdx.x * 2 + (wid >> 1);
    const int m0 = strip * 16;                  // this wave's 16-row strip
    const int nb0 = (wid & 1) * 8;              // this wave's n-block half

    // A fragments: a[kb][j] = bf16(x[m0+lr][kb*32 + hi*8 + j])
    short8 a[8];
    const float* __restrict__ xr = x + (size_t)(m0 + lr) * C_DIM;
#pragma unroll
    for (int kb = 0; kb < 8; ++kb) {
        const f32x4* p = reinterpret_cast<const f32x4*>(xr + kb * 32 + hi * 8);
        f32x4 u = p[0];
        f32x4 v = p[1];
        short8 t;
#pragma unroll
        for (int j = 0; j < 4; ++j) {
            t[j]     = f2bf(u[j]);
            t[4 + j] = f2bf(v[j]);
        }
        a[kb] = t;
    }

    const short8* __restrict__ wp8 = reinterpret_cast<const short8*>(wpack);
#pragma unroll 4
    for (int nbi = 0; nbi < 8; ++nbi) {
        const int nb = nb0 + nbi;
        f32x4 acc = {0.f, 0.f, 0.f, 0.f};
#pragma unroll
        for (int kb = 0; kb < 8; ++kb) {
            short8 b = wp8[(nb * 8 + kb) * 64 + lane];
            acc = __builtin_amdgcn_mfma_f32_16x16x32_bf16(a[kb], b, acc, 0, 0, 0);
        }
        const float bias = b_proj[nb * 16 + lr];
        // C/D layout (measured): col = lane&15, row = (lane>>4)*4 + reg
#pragma unroll
        for (int r = 0; r < 4; ++r) {
            out[(size_t)(m0 + hi * 4 + r) * C_DIM + nb * 16 + lr] = acc[r] + bias;
        }
    }
}

extern "C" void kernel_launch(void* const* d_in, const int* in_sizes, int n_in,
                              void* d_out, int out_size, void* d_ws, size_t ws_size,
                              hipStream_t stream) {
    const float* x      = (const float*)d_in[0];   // [2,4096,256]
    const float* w_qkv  = (const float*)d_in[1];   // [768,256]
    const float* w_proj = (const float*)d_in[2];   // [256,256]
    const float* b_proj = (const float*)d_in[3];   // [256]
    // d_in[4] = temperature: softmax is exactly one-hot for any T>0 -> unused.
    short* wpack = (short*)d_ws;                   // 256*256 bf16 = 128 KB
    float* out = (float*)d_out;

    hipLaunchKernelGGL(weff_pack_kernel, dim3(256), dim3(256), 0, stream,
                       w_qkv, w_proj, wpack);
    hipLaunchKernelGGL(out_gemm_kernel, dim3(M_ROWS / 32), dim3(256), 0, stream,
                       x, wpack, b_proj, out);
}